// Round 2
// baseline (168.456 us; speedup 1.0000x reference)
//
#include <hip/hip_runtime.h>
#include <math.h>

#define BB 8
#define SS 4096
#define DD 1024
#define KK 3072

typedef unsigned long long u64;
typedef unsigned int u32;

// ---------------- Kernel 1: scores + sortable keys --------------------------------
// One wave (64 lanes) per token row. 1024 floats = 256 float4; 4 float4/lane.
// key = (~mono(score) << 32) | in-batch-index : ascending key == descending score,
// ties broken by lower index (matches lax.top_k stable order).
__global__ __launch_bounds__(256) void mod_scores(const float* __restrict__ x,
                                                  const float* __restrict__ w,
                                                  float* __restrict__ scores,
                                                  u64* __restrict__ keys) {
    int wave = (int)((blockIdx.x * blockDim.x + threadIdx.x) >> 6);
    int lane = threadIdx.x & 63;
    if (wave >= BB * SS) return;
    const float4* xr = (const float4*)(x + (size_t)wave * DD);
    const float4* wr = (const float4*)w;
    float acc = 0.f;
#pragma unroll
    for (int i = 0; i < 4; ++i) {
        float4 a = xr[lane + 64 * i];
        float4 b = wr[lane + 64 * i];
        acc += a.x * b.x + a.y * b.y + a.z * b.z + a.w * b.w;
    }
#pragma unroll
    for (int off = 32; off > 0; off >>= 1)
        acc += __shfl_down(acc, off, 64);
    if (lane == 0) {
        scores[wave] = acc;
        u32 u = __float_as_uint(acc);
        u32 m = (u & 0x80000000u) ? ~u : (u | 0x80000000u);  // monotonic ascending
        keys[wave] = ((u64)(~m) << 32) | (u32)(wave & (SS - 1));
    }
}

// ---------------- Kernel 2: all-pairs rank + partial softmax denominator ----------
// One thread per element; scans its batch's 4096 keys (wave-uniform index ->
// scalar s_load path). rank = #{k : key_k < key_i}. No barrier-heavy sort.
// partial[block] = sum over this block's top-K elements of exp(score).
__global__ __launch_bounds__(256) void mod_rank(const u64* __restrict__ keys,
                                                const float* __restrict__ scores,
                                                int* __restrict__ rank_of,
                                                float* __restrict__ partial) {
    const int gid = blockIdx.x * 256 + threadIdx.x;   // 0..32767
    const int b = gid >> 12;
    const u64* __restrict__ kb = keys + ((size_t)b << 12);
    const u64 my = keys[gid];
    int cnt = 0;
#pragma unroll 16
    for (int k = 0; k < SS; ++k)
        cnt += (kb[k] < my) ? 1 : 0;
    rank_of[gid] = cnt;

    float e = (cnt < KK) ? expf(scores[gid]) : 0.f;
    __shared__ float red[256];
    red[threadIdx.x] = e;
    __syncthreads();
    for (int off = 128; off > 0; off >>= 1) {
        if (threadIdx.x < off) red[threadIdx.x] += red[threadIdx.x + off];
        __syncthreads();
    }
    if (threadIdx.x == 0) partial[blockIdx.x] = red[0];
}

// ---------------- Kernel 3: blend/copy per token row ------------------------------
// One block (256 threads) per (b,s) row. Weight computed inline:
// w = exp(score)/denom (no max-subtraction needed; |score| small).
__global__ __launch_bounds__(256) void mod_blend(const float* __restrict__ x,
                                                 const float* __restrict__ proc,
                                                 const int* __restrict__ rank_of,
                                                 const float* __restrict__ scores,
                                                 const float* __restrict__ partial,
                                                 float* __restrict__ out) {
    const int row = blockIdx.x;           // b*S + s
    const int b = row >> 12;
    const int t = threadIdx.x;
    const float4* xr = (const float4*)(x + (size_t)row * DD);
    float4* orow = (float4*)(out + (size_t)row * DD);
    const int j = rank_of[row];           // uniform per block -> scalar load
    float4 a = xr[t];
    if (j < KK) {
        float denom = 0.f;
#pragma unroll
        for (int i = 0; i < 16; ++i) denom += partial[b * 16 + i];  // deterministic
        float w = expf(scores[row]) / denom;
        const float4* pr = (const float4*)(proc + ((size_t)b * KK + j) * DD);
        float4 p = pr[t];
        float4 o;
        o.x = p.x * w + (1.f - w) * a.x;
        o.y = p.y * w + (1.f - w) * a.y;
        o.z = p.z * w + (1.f - w) * a.z;
        o.w = p.w * w + (1.f - w) * a.w;
        orow[t] = o;
    } else {
        orow[t] = a;
    }
}

extern "C" void kernel_launch(void* const* d_in, const int* in_sizes, int n_in,
                              void* d_out, int out_size, void* d_ws, size_t ws_size,
                              hipStream_t stream) {
    const float* x    = (const float*)d_in[0];   // (B,S,D)
    const float* proc = (const float*)d_in[1];   // (B,K,D)
    const float* w    = (const float*)d_in[2];   // (D,)
    float* out = (float*)d_out;

    // workspace layout (keys first for 8B alignment)
    u64*   keys    = (u64*)d_ws;                                  // 32768 u64 (256 KB)
    float* scores  = (float*)((char*)d_ws + BB * SS * 8);         // 32768 f32 (128 KB)
    int*   rank_of = (int*)((char*)d_ws + BB * SS * 12);          // 32768 i32 (128 KB)
    float* partial = (float*)((char*)d_ws + BB * SS * 16);        // 128 f32
    // total ~512.5 KB

    mod_scores<<<(BB * SS) / 4, 256, 0, stream>>>(x, w, scores, keys);
    mod_rank  <<<(BB * SS) / 256, 256, 0, stream>>>(keys, scores, rank_of, partial);
    mod_blend <<<BB * SS, 256, 0, stream>>>(x, proc, rank_of, scores, partial, out);
}

// Round 3
// 94.104 us; speedup vs baseline: 1.7901x; 1.7901x over previous
//
#include <hip/hip_runtime.h>
#include <math.h>

#define BB 8
#define SS 4096
#define DD 1024
#define KK 3072
#define NCHUNK 8
#define CHUNK 512          // SS / NCHUNK
#define NELEM (BB * SS)    // 32768

typedef unsigned long long u64;
typedef unsigned int u32;

// ---------------- Kernel 1: scores + sortable keys --------------------------------
// One wave (64 lanes) per token row. key = (~mono(score) << 32) | index :
// ascending key == descending score, ties by lower index (lax.top_k stable order).
__global__ __launch_bounds__(256) void mod_scores(const float* __restrict__ x,
                                                  const float* __restrict__ w,
                                                  float* __restrict__ scores,
                                                  u64* __restrict__ keys) {
    int wave = (int)((blockIdx.x * blockDim.x + threadIdx.x) >> 6);
    int lane = threadIdx.x & 63;
    if (wave >= NELEM) return;
    const float4* xr = (const float4*)(x + (size_t)wave * DD);
    const float4* wr = (const float4*)w;
    float acc = 0.f;
#pragma unroll
    for (int i = 0; i < 4; ++i) {
        float4 a = xr[lane + 64 * i];
        float4 b = wr[lane + 64 * i];
        acc += a.x * b.x + a.y * b.y + a.z * b.z + a.w * b.w;
    }
#pragma unroll
    for (int off = 32; off > 0; off >>= 1)
        acc += __shfl_down(acc, off, 64);
    if (lane == 0) {
        scores[wave] = acc;
        u32 u = __float_as_uint(acc);
        u32 m = (u & 0x80000000u) ? ~u : (u | 0x80000000u);  // monotonic ascending
        keys[wave] = ((u64)(~m) << 32) | (u32)(wave & (SS - 1));
    }
}

// ---------------- Kernel 2: tiled partial rank ------------------------------------
// Block = (owner-block ob, chunk c). 256 owner threads; 512 candidates staged in LDS.
// pcnt[c*NELEM + gid] = #{candidates in chunk c with key < key_gid}.
__global__ __launch_bounds__(256) void mod_rank_partial(const u64* __restrict__ keys,
                                                        int* __restrict__ pcnt) {
    __shared__ u64 lk[CHUNK];
    const int ob = blockIdx.x / NCHUNK;
    const int c  = blockIdx.x - ob * NCHUNK;
    const int tid = threadIdx.x;
    const int gid = ob * 256 + tid;
    const int b = gid >> 12;

    const u64* __restrict__ cand = keys + ((size_t)b << 12) + c * CHUNK;
    lk[tid]       = cand[tid];
    lk[tid + 256] = cand[tid + 256];
    __syncthreads();

    const u64 my = keys[gid];
    int cnt = 0;
#pragma unroll 8
    for (int k = 0; k < CHUNK; ++k)
        cnt += (lk[k] < my) ? 1 : 0;          // broadcast LDS read, conflict-free
    pcnt[c * NELEM + gid] = cnt;
}

// ---------------- Kernel 3: finalize rank + partial softmax denominator -----------
// 128 blocks of 256; rank = sum of 8 partials; partial[block] = sum exp(score) over
// this block's top-K members (deterministic; blend sums the 16 per batch).
__global__ __launch_bounds__(256) void mod_finalize(const int* __restrict__ pcnt,
                                                    const float* __restrict__ scores,
                                                    int* __restrict__ rank_of,
                                                    float* __restrict__ partial) {
    const int gid = blockIdx.x * 256 + threadIdx.x;
    int r = 0;
#pragma unroll
    for (int c = 0; c < NCHUNK; ++c) r += pcnt[c * NELEM + gid];
    rank_of[gid] = r;

    float e = (r < KK) ? expf(scores[gid]) : 0.f;
    __shared__ float red[256];
    red[threadIdx.x] = e;
    __syncthreads();
    for (int off = 128; off > 0; off >>= 1) {
        if (threadIdx.x < off) red[threadIdx.x] += red[threadIdx.x + off];
        __syncthreads();
    }
    if (threadIdx.x == 0) partial[blockIdx.x] = red[0];
}

// ---------------- Kernel 4: blend/copy per token row ------------------------------
__global__ __launch_bounds__(256) void mod_blend(const float* __restrict__ x,
                                                 const float* __restrict__ proc,
                                                 const int* __restrict__ rank_of,
                                                 const float* __restrict__ scores,
                                                 const float* __restrict__ partial,
                                                 float* __restrict__ out) {
    const int row = blockIdx.x;           // b*S + s
    const int b = row >> 12;
    const int t = threadIdx.x;
    const float4* xr = (const float4*)(x + (size_t)row * DD);
    float4* orow = (float4*)(out + (size_t)row * DD);
    const int j = rank_of[row];           // uniform per block -> scalar load
    float4 a = xr[t];
    if (j < KK) {
        float denom = 0.f;
#pragma unroll
        for (int i = 0; i < 16; ++i) denom += partial[b * 16 + i];  // deterministic
        float w = expf(scores[row]) / denom;
        const float4* pr = (const float4*)(proc + ((size_t)b * KK + j) * DD);
        float4 p = pr[t];
        float4 o;
        o.x = p.x * w + (1.f - w) * a.x;
        o.y = p.y * w + (1.f - w) * a.y;
        o.z = p.z * w + (1.f - w) * a.z;
        o.w = p.w * w + (1.f - w) * a.w;
        orow[t] = o;
    } else {
        orow[t] = a;
    }
}

extern "C" void kernel_launch(void* const* d_in, const int* in_sizes, int n_in,
                              void* d_out, int out_size, void* d_ws, size_t ws_size,
                              hipStream_t stream) {
    const float* x    = (const float*)d_in[0];   // (B,S,D)
    const float* proc = (const float*)d_in[1];   // (B,K,D)
    const float* w    = (const float*)d_in[2];   // (D,)
    float* out = (float*)d_out;

    // workspace layout
    u64*   keys    = (u64*)d_ws;                                   // 256 KB
    float* scores  = (float*)((char*)d_ws + NELEM * 8);            // 128 KB
    int*   rank_of = (int*)((char*)d_ws + NELEM * 12);             // 128 KB
    int*   pcnt    = (int*)((char*)d_ws + NELEM * 16);             // 1 MB
    float* partial = (float*)((char*)d_ws + NELEM * 16 + NELEM * 4 * NCHUNK); // 512 B

    mod_scores      <<<NELEM / 4, 256, 0, stream>>>(x, w, scores, keys);
    mod_rank_partial<<<(NELEM / 256) * NCHUNK, 256, 0, stream>>>(keys, pcnt);
    mod_finalize    <<<NELEM / 256, 256, 0, stream>>>(pcnt, scores, rank_of, partial);
    mod_blend       <<<NELEM, 256, 0, stream>>>(x, proc, rank_of, scores, partial, out);
}

// Round 5
// 93.345 us; speedup vs baseline: 1.8047x; 1.0081x over previous
//
#include <hip/hip_runtime.h>
#include <math.h>

#define BB 8
#define SS 4096
#define DD 1024
#define KK 3072
#define NCHUNK 8
#define CHUNK 512          // SS / NCHUNK candidates per block
#define NELEM (BB * SS)    // 32768

typedef unsigned long long u64;
typedef unsigned int u32;

// ---------------- Kernel 1: scores + sortable keys --------------------------------
// One wave (64 lanes) per token row. key = (~mono(score) << 32) | index :
// ascending key == descending score, ties by lower index (lax.top_k stable order).
__global__ __launch_bounds__(256) void mod_scores(const float* __restrict__ x,
                                                  const float* __restrict__ w,
                                                  float* __restrict__ scores,
                                                  u64* __restrict__ keys) {
    int wave = (int)((blockIdx.x * blockDim.x + threadIdx.x) >> 6);
    int lane = threadIdx.x & 63;
    if (wave >= NELEM) return;
    const float4* xr = (const float4*)(x + (size_t)wave * DD);
    const float4* wr = (const float4*)w;
    float acc = 0.f;
#pragma unroll
    for (int i = 0; i < 4; ++i) {
        float4 a = xr[lane + 64 * i];
        float4 b = wr[lane + 64 * i];
        acc += a.x * b.x + a.y * b.y + a.z * b.z + a.w * b.w;
    }
#pragma unroll
    for (int off = 32; off > 0; off >>= 1)
        acc += __shfl_down(acc, off, 64);
    if (lane == 0) {
        scores[wave] = acc;
        u32 u = __float_as_uint(acc);
        u32 m = (u & 0x80000000u) ? ~u : (u | 0x80000000u);  // monotonic ascending
        keys[wave] = ((u64)(~m) << 32) | (u32)(wave & (SS - 1));
    }
}

// ---------------- Kernel 2: tiled partial rank (ballot-vectorized) ----------------
// Block = (owner-block ob, chunk c). 256 owner threads; 512 candidates staged in LDS.
// Lane-strided candidate reads (1 ds_read_b64 per 64 candidates per wave); owners
// broadcast via readlane to SGPRs; v_cmp_lt_u64 + ballot/popc = 64 pairs/instr.
// cnt is wave-uniform -> each lane selects its own owner's count (no writelane).
// pcnt[c*NELEM + gid] = #{candidates in chunk c with key < key_gid}.
__global__ __launch_bounds__(256) void mod_rank_partial(const u64* __restrict__ keys,
                                                        int* __restrict__ pcnt) {
    __shared__ __align__(16) u64 lk[CHUNK];
    const int ob = blockIdx.x / NCHUNK;
    const int c  = blockIdx.x - ob * NCHUNK;
    const int tid = threadIdx.x;
    const int gid = ob * 256 + tid;
    const int b = gid >> 12;
    const int lane = tid & 63;

    const u64* __restrict__ cand = keys + ((size_t)b << 12) + c * CHUNK;
    // stage 4 KB: 16 B per thread
    *(ulonglong2*)&lk[tid * 2] = *(const ulonglong2*)&cand[tid * 2];
    __syncthreads();

    const u64 my = keys[gid];
    const u32 my_hi = (u32)(my >> 32);
    const u32 my_lo = (u32)my;

    int v_cnt = 0;   // lane i ends up holding owner-i's count
#pragma unroll
    for (int g = 0; g < 8; ++g) {
        // hoist owner keys for lanes g*8 .. g*8+7 into (uniform) scalars
        u64 mj[8];
#pragma unroll
        for (int j = 0; j < 8; ++j) {
            u32 h = (u32)__builtin_amdgcn_readlane((int)my_hi, g * 8 + j);
            u32 l = (u32)__builtin_amdgcn_readlane((int)my_lo, g * 8 + j);
            mj[j] = ((u64)h << 32) | l;
        }
        int cnt[8] = {0, 0, 0, 0, 0, 0, 0, 0};
#pragma unroll
        for (int cg = 0; cg < CHUNK / 64; ++cg) {   // 8 iterations
            u64 cv = lk[cg * 64 + lane];            // lane-strided: 64 cands / read
#pragma unroll
            for (int j = 0; j < 8; ++j)
                cnt[j] += (int)__popcll(__ballot(cv < mj[j]));  // 64 pairs / v_cmp
        }
        // cnt[j] is wave-uniform; owner lane g*8+j keeps it
#pragma unroll
        for (int j = 0; j < 8; ++j)
            v_cnt = (lane == g * 8 + j) ? cnt[j] : v_cnt;
    }
    pcnt[c * NELEM + gid] = v_cnt;
}

// ---------------- Kernel 3: finalize rank + partial softmax denominator -----------
// 128 blocks of 256; rank = sum of 8 partials; partial[block] = sum exp(score) over
// this block's top-K members (deterministic; blend sums the 16 per batch).
__global__ __launch_bounds__(256) void mod_finalize(const int* __restrict__ pcnt,
                                                    const float* __restrict__ scores,
                                                    int* __restrict__ rank_of,
                                                    float* __restrict__ partial) {
    const int gid = blockIdx.x * 256 + threadIdx.x;
    int r = 0;
#pragma unroll
    for (int c = 0; c < NCHUNK; ++c) r += pcnt[c * NELEM + gid];
    rank_of[gid] = r;

    float e = (r < KK) ? expf(scores[gid]) : 0.f;
    __shared__ float red[256];
    red[threadIdx.x] = e;
    __syncthreads();
    for (int off = 128; off > 0; off >>= 1) {
        if (threadIdx.x < off) red[threadIdx.x] += red[threadIdx.x + off];
        __syncthreads();
    }
    if (threadIdx.x == 0) partial[blockIdx.x] = red[0];
}

// ---------------- Kernel 4: blend/copy per token row ------------------------------
__global__ __launch_bounds__(256) void mod_blend(const float* __restrict__ x,
                                                 const float* __restrict__ proc,
                                                 const int* __restrict__ rank_of,
                                                 const float* __restrict__ scores,
                                                 const float* __restrict__ partial,
                                                 float* __restrict__ out) {
    const int row = blockIdx.x;           // b*S + s
    const int b = row >> 12;
    const int t = threadIdx.x;
    const float4* xr = (const float4*)(x + (size_t)row * DD);
    float4* orow = (float4*)(out + (size_t)row * DD);
    const int j = rank_of[row];           // uniform per block -> scalar load
    float4 a = xr[t];
    if (j < KK) {
        float denom = 0.f;
#pragma unroll
        for (int i = 0; i < 16; ++i) denom += partial[b * 16 + i];  // deterministic
        float w = expf(scores[row]) / denom;
        const float4* pr = (const float4*)(proc + ((size_t)b * KK + j) * DD);
        float4 p = pr[t];
        float4 o;
        o.x = p.x * w + (1.f - w) * a.x;
        o.y = p.y * w + (1.f - w) * a.y;
        o.z = p.z * w + (1.f - w) * a.z;
        o.w = p.w * w + (1.f - w) * a.w;
        orow[t] = o;
    } else {
        orow[t] = a;
    }
}

extern "C" void kernel_launch(void* const* d_in, const int* in_sizes, int n_in,
                              void* d_out, int out_size, void* d_ws, size_t ws_size,
                              hipStream_t stream) {
    const float* x    = (const float*)d_in[0];   // (B,S,D)
    const float* proc = (const float*)d_in[1];   // (B,K,D)
    const float* w    = (const float*)d_in[2];   // (D,)
    float* out = (float*)d_out;

    // workspace layout
    u64*   keys    = (u64*)d_ws;                                   // 256 KB
    float* scores  = (float*)((char*)d_ws + NELEM * 8);            // 128 KB
    int*   rank_of = (int*)((char*)d_ws + NELEM * 12);             // 128 KB
    int*   pcnt    = (int*)((char*)d_ws + NELEM * 16);             // 1 MB
    float* partial = (float*)((char*)d_ws + NELEM * 16 + NELEM * 4 * NCHUNK); // 512 B

    mod_scores      <<<NELEM / 4, 256, 0, stream>>>(x, w, scores, keys);
    mod_rank_partial<<<(NELEM / 256) * NCHUNK, 256, 0, stream>>>(keys, pcnt);
    mod_finalize    <<<NELEM / 256, 256, 0, stream>>>(pcnt, scores, rank_of, partial);
    mod_blend       <<<NELEM, 256, 0, stream>>>(x, proc, rank_of, scores, partial, out);
}